// Round 6
// baseline (259.817 us; speedup 1.0000x reference)
//
#include <hip/hip_runtime.h>
#include <hip/hip_bf16.h>
#include <cstddef>

// Problem constants (SelfAttention: B=4, T=2048, H=16, Dh=64, C=1024)
#define B_  4
#define T_  2048
#define H_  16
#define DH  64
#define C_  1024
#define BH  64    // B_*H_

typedef float  f32x16 __attribute__((ext_vector_type(16)));
typedef __bf16 bf16x8 __attribute__((ext_vector_type(8)));
typedef __bf16 bf16x4 __attribute__((ext_vector_type(4)));

#define MFMA32(a, b, c) __builtin_amdgcn_mfma_f32_32x32x16_bf16(a, b, c, 0, 0, 0)

// mfma_f32_32x32x16_bf16 layouts (cdna4_isa / m74,m101 verified C/D):
//   A[m][k]: m = lane&31, k = (lane>>5)*8 + j   (8 bf16 per lane, b128)
//   B[k][n]: n = lane&31, k = (lane>>5)*8 + j
//   C/D:     col = lane&31, row = (reg&3) + 8*(reg>>2) + 4*(lane>>5)
//
// K/V are stored FRAGMENT-MAJOR in global:
//   Kf[bh][kt64][rh][ks][lane][8]  (elem = K[kt64*64+rh*32+(lane&31)][ks*16+(lane>>5)*8+j])
//   Vf[bh][kt64][dh][c ][lane][8]  (elem = V^T[dh*32+(lane&31)][kt64*64+c*16+(lane>>5)*8+j])
// so an attention fragment load is base + lane*16B: ONE coalesced 1KB
// transaction.

__device__ __forceinline__ unsigned cvt_pk_bf16(float lo, float hi) {
    unsigned r;
    asm("v_cvt_pk_bf16_f32 %0, %1, %2" : "=v"(r) : "v"(lo), "v"(hi));
    return r;
}

// ---------------------------------------------------------------------------
// Kernel 0: Wq/Wk/Wv fp32 -> bf16 pre-conversion (once; into dead ows region).
// Removes the per-block f32 staging + packing VALU from all 1024 qkv blocks.
// ---------------------------------------------------------------------------
__global__ __launch_bounds__(256) void wconv_kernel(
    const float* __restrict__ Wq, const float* __restrict__ Wk,
    const float* __restrict__ Wv, __bf16* __restrict__ wqkv)
{
    const int tid = blockIdx.x * 256 + threadIdx.x;   // 0..3071
    const float* srcs[3] = {Wq, Wk, Wv};
    const int mat = tid >> 10;                        // 1024 threads per matrix
    const int off = (tid & 1023) * 4;
    const float4 w4 = *(const float4*)(srcs[mat] + off);
    const unsigned lo = ((unsigned)__builtin_bit_cast(unsigned short, (__bf16)w4.y) << 16)
                      | (unsigned)__builtin_bit_cast(unsigned short, (__bf16)w4.x);
    const unsigned hi = ((unsigned)__builtin_bit_cast(unsigned short, (__bf16)w4.w) << 16)
                      | (unsigned)__builtin_bit_cast(unsigned short, (__bf16)w4.z);
    uint2 p; p.x = lo; p.y = hi;
    *(uint2*)(wqkv + mat * 4096 + off) = p;
}

// ---------------------------------------------------------------------------
// Kernel 1: QKV projection, bf16 MFMA. Block = (128-token tile, one head).
// q written [bh][t][d] with (1/sqrt(C))*log2(e) folded (attention uses exp2).
// k and v written fragment-major (see above) via LDS transposes.
// Weights arrive pre-converted bf16 (wqkv): staging is 6 plain 16B copies.
// ---------------------------------------------------------------------------
__global__ __launch_bounds__(256) void qkv_kernel(
    const float* __restrict__ x,
    const __bf16* __restrict__ wqkv,
    const float* __restrict__ bq, const float* __restrict__ bk,
    const float* __restrict__ bv,
    __bf16* __restrict__ q, __bf16* __restrict__ kf, __bf16* __restrict__ vf)
{
    __shared__ __bf16 Xs[128 * 72];          // x tile [t_local][d], bf16
    __shared__ __bf16 Ws[3][64 * 72];        // W[e][d], bf16
    __bf16* Vtl = Xs;                         // alias: V^T [e][t_local], stride 136
    __bf16* Kst = &Ws[0][0];                  // alias after mat loop: K [t_local][d], stride 72

    const int tt  = blockIdx.x;               // 0..15 (128-token tile)
    const int bh  = blockIdx.y;               // 0..63
    const int b   = bh >> 4, h = bh & 15;
    const int t0  = tt * 128;
    const int tid = threadIdx.x;
    const int wave = tid >> 6, lane = tid & 63;
    const int m = lane & 31, hh = lane >> 5;

    // stage x (fp32 -> bf16): 128 rows x 64 cols = 2048 float4 chunks
    #pragma unroll
    for (int i = 0; i < 8; ++i) {
        const int idx = i * 256 + tid;
        const int r = idx >> 4, c = (idx & 15) * 4;
        const float4 x4 = *(const float4*)(x + ((size_t)(b * T_ + t0 + r)) * C_ + h * DH + c);
        const unsigned lo = ((unsigned)__builtin_bit_cast(unsigned short, (__bf16)x4.y) << 16)
                          | (unsigned)__builtin_bit_cast(unsigned short, (__bf16)x4.x);
        const unsigned hi = ((unsigned)__builtin_bit_cast(unsigned short, (__bf16)x4.w) << 16)
                          | (unsigned)__builtin_bit_cast(unsigned short, (__bf16)x4.z);
        *(unsigned*)&Xs[r * 72 + c]     = lo;
        *(unsigned*)&Xs[r * 72 + c + 2] = hi;
    }
    // stage weights (already bf16): 3 x 64 x 64 = 1536 uint4 chunks
    #pragma unroll
    for (int i = 0; i < 6; ++i) {
        const int idx = i * 256 + tid;
        const int mat_ = idx >> 9;            // 0..2
        const int r = (idx >> 3) & 63, c = (idx & 7) * 8;
        *(uint4*)&Ws[mat_][r * 72 + c] = *(const uint4*)(wqkv + mat_ * 4096 + r * 64 + c);
    }
    __syncthreads();

    // hoist x A-fragments (wave-private rows 32*wave + m)
    bf16x8 xf[4];
    #pragma unroll
    for (int ks = 0; ks < 4; ++ks)
        xf[ks] = *(const bf16x8*)&Xs[(wave * 32 + m) * 72 + ks * 16 + hh * 8];
    __syncthreads();   // all frag reads done before Vtl aliases Xs

    // 1/sqrt(1024) * log2(e) folded into q (attention uses exp2 directly)
    const float s32 = 0.03125f * 1.4426950408889634f;

    unsigned kpk[16];   // packed k results, staged to LDS after the mat loop

    #pragma unroll
    for (int mat = 0; mat < 3; ++mat) {
        f32x16 acc0 = {}, acc1 = {};
        #pragma unroll
        for (int ks = 0; ks < 4; ++ks) {
            const bf16x8 w0 = *(const bf16x8*)&Ws[mat][(m) * 72 + ks * 16 + hh * 8];
            const bf16x8 w1 = *(const bf16x8*)&Ws[mat][(32 + m) * 72 + ks * 16 + hh * 8];
            acc0 = MFMA32(xf[ks], w0, acc0);
            acc1 = MFMA32(xf[ks], w1, acc1);
        }
        const float* bias = (mat == 0) ? bq : (mat == 1) ? bk : bv;
        const float b0 = bias[m], b1 = bias[32 + m];
        #pragma unroll
        for (int r = 0; r < 16; ++r) {
            const int R = (r & 3) + 8 * (r >> 2) + 4 * hh;   // token row in tile
            const int tloc = wave * 32 + R;
            const float v0 = acc0[r] + b0, v1 = acc1[r] + b1;
            if (mat == 0) {
                const size_t base = ((size_t)bh * T_ + t0 + tloc) * DH;
                q[base + m]      = (__bf16)(v0 * s32);
                q[base + 32 + m] = (__bf16)(v1 * s32);
            } else if (mat == 1) {
                kpk[r] = ((unsigned)__builtin_bit_cast(unsigned short, (__bf16)v1) << 16)
                       |  (unsigned)__builtin_bit_cast(unsigned short, (__bf16)v0);
            } else {
                Vtl[(m) * 136 + tloc]      = (__bf16)v0;   // V^T [e][t_local]
                Vtl[(32 + m) * 136 + tloc] = (__bf16)v1;
            }
        }
    }
    __syncthreads();   // Ws reads done (mat loop), Vtl complete

    // stage k tile [t_local][d] into Kst (Ws area, now dead)
    #pragma unroll
    for (int r = 0; r < 16; ++r) {
        const int R = (r & 3) + 8 * (r >> 2) + 4 * hh;
        const int tloc = wave * 32 + R;
        Kst[tloc * 72 + m]      = __builtin_bit_cast(__bf16, (unsigned short)(kpk[r] & 0xffff));
        Kst[tloc * 72 + 32 + m] = __builtin_bit_cast(__bf16, (unsigned short)(kpk[r] >> 16));
    }

    // Vf fragment-major out (reads Vtl; no barrier needed vs Kst region)
    // 2 kt64 x 2 dh x 4 c x 64 lanes = 1024 uint4 chunks / 256 threads
    #pragma unroll
    for (int i = 0; i < 4; ++i) {
        const int idx = i * 256 + tid;
        const int ln = idx & 63, c_ = idx >> 6;           // c_ 0..15
        const int kt64l = c_ >> 3, dh = (c_ >> 2) & 1, cN = c_ & 3;
        const __bf16* src = &Vtl[(dh * 32 + (ln & 31)) * 136 + kt64l * 64 + cN * 16 + (ln >> 5) * 8];
        __bf16* dst = vf + ((((size_t)(bh * 32 + tt * 2 + kt64l) * 2 + dh) * 4 + cN) * 64 + ln) * 8;
        *(uint4*)dst = *(const uint4*)src;
    }
    __syncthreads();   // Kst visible

    // Kf fragment-major out (reads Kst)
    #pragma unroll
    for (int i = 0; i < 4; ++i) {
        const int idx = i * 256 + tid;
        const int ln = idx & 63, c_ = idx >> 6;
        const int kt64l = c_ >> 3, rh = (c_ >> 2) & 1, ks = c_ & 3;
        const __bf16* src = &Kst[(kt64l * 64 + rh * 32 + (ln & 31)) * 72 + ks * 16 + (ln >> 5) * 8];
        __bf16* dst = kf + ((((size_t)(bh * 32 + tt * 2 + kt64l) * 2 + rh) * 4 + ks) * 64 + ln) * 8;
        *(uint4*)dst = *(const uint4*)src;
    }
}

// ---------------------------------------------------------------------------
// Kernel 2: flash attention (UNCHANGED from round 5: 91 us, MfmaUtil 32%).
// Swapped-operand in-register softmax; K/V read fragment-major from global
// (coalesced 1KB loads, L2-resident via bh-on-x XCD mapping) -- no LDS /
// barriers in the main loop. Grid (64 bh, 16 q-tiles) = 4 blocks/CU.
// ---------------------------------------------------------------------------
__global__ __launch_bounds__(256, 4) void attn_kernel(
    const __bf16* __restrict__ q, const __bf16* __restrict__ kf,
    const __bf16* __restrict__ vf, __bf16* __restrict__ o)
{
    __shared__ __bf16 Os[128 * 72];          // epilogue transpose buffer

    const int bh  = blockIdx.x;              // XCD-locality axis (id%8 == bh%8)
    const int q0  = blockIdx.y * 128;
    const int tid = threadIdx.x;
    const int wave = tid >> 6, lane = tid & 63;
    const int m = lane & 31, h = lane >> 5;

    const __bf16* qb  = q  + (size_t)bh * T_ * DH;
    const __bf16* kfb = kf + (size_t)bh * (T_ * DH);   // [kt64][rh][ks][lane][8]
    const __bf16* vfb = vf + (size_t)bh * (T_ * DH);   // [kt64][dh][c ][lane][8]

    // Q fragments (one-time; [t][d] layout, segmented but negligible)
    bf16x8 qf[4];
    #pragma unroll
    for (int ks = 0; ks < 4; ++ks)
        qf[ks] = *(const bf16x8*)(qb + (size_t)(q0 + wave * 32 + m) * DH + ks * 16 + h * 8);

    f32x16 O0 = {}, O1 = {};                 // O^T [d 0..31 | 32..63][q]
    float lsum = 0.f;

    for (int kt = 0; kt < 32; ++kt) {
        const __bf16* kt_k = kfb + kt * 4096;
        const __bf16* kt_v = vfb + kt * 4096;
        #pragma unroll
        for (int rh = 0; rh < 2; ++rh) {
            bf16x8 kfr[4];
            #pragma unroll
            for (int ks = 0; ks < 4; ++ks)
                kfr[ks] = *(const bf16x8*)(kt_k + rh * 2048 + ks * 512 + lane * 8);
            f32x16 S = {};
            #pragma unroll
            for (int ks = 0; ks < 4; ++ks)
                S = MFMA32(kfr[ks], qf[ks], S);

            #pragma unroll
            for (int cc = 0; cc < 2; ++cc) {
                const int rb = cc * 8;
                float e0 = __builtin_amdgcn_exp2f(S[rb + 0]);
                float e1 = __builtin_amdgcn_exp2f(S[rb + 1]);
                float e2 = __builtin_amdgcn_exp2f(S[rb + 2]);
                float e3 = __builtin_amdgcn_exp2f(S[rb + 3]);
                float e4 = __builtin_amdgcn_exp2f(S[rb + 4]);
                float e5 = __builtin_amdgcn_exp2f(S[rb + 5]);
                float e6 = __builtin_amdgcn_exp2f(S[rb + 6]);
                float e7 = __builtin_amdgcn_exp2f(S[rb + 7]);
                lsum += ((e0 + e1) + (e2 + e3)) + ((e4 + e5) + (e6 + e7));
                unsigned a0 = cvt_pk_bf16(e0, e1);
                unsigned a1 = cvt_pk_bf16(e2, e3);
                unsigned b0 = cvt_pk_bf16(e4, e5);
                unsigned b1 = cvt_pk_bf16(e6, e7);
                asm("v_permlane32_swap_b32 %0, %1" : "+v"(a0), "+v"(b0));
                asm("v_permlane32_swap_b32 %0, %1" : "+v"(a1), "+v"(b1));
                const uint4 pw = {a0, a1, b0, b1};
                const bf16x8 pb = __builtin_bit_cast(bf16x8, pw);
                const int c = rh * 2 + cc;          // kv 16-slot
                const bf16x8 v0 = *(const bf16x8*)(kt_v + c * 512 + lane * 8);
                const bf16x8 v1 = *(const bf16x8*)(kt_v + 2048 + c * 512 + lane * 8);
                O0 = MFMA32(v0, pb, O0);
                O1 = MFMA32(v1, pb, O1);
            }
        }
    }

    // l[q]: lanes l and l+32 hold complementary kv halves of the same q-row
    lsum += __shfl_xor(lsum, 32);
    const float linv = 1.0f / lsum;

    // O^T -> LDS: lane owns q-row (wave*32 + m); reg r -> d = (r&3)+8*(r>>2)+4h
    #pragma unroll
    for (int g = 0; g < 4; ++g) {
        bf16x4 w0, w1;
        #pragma unroll
        for (int j = 0; j < 4; ++j) {
            w0[j] = (__bf16)(O0[4 * g + j] * linv);
            w1[j] = (__bf16)(O1[4 * g + j] * linv);
        }
        const int row = (wave * 32 + m) * 72;
        *(bf16x4*)&Os[row + 8 * g + 4 * h]      = w0;
        *(bf16x4*)&Os[row + 32 + 8 * g + 4 * h] = w1;
    }
    __syncthreads();

    // fully coalesced store: 128 rows x 64 bf16 = 1024 uint4 / 256 threads
    __bf16* ob = o + ((size_t)bh * T_ + q0) * DH;
    #pragma unroll
    for (int i = 0; i < 4; ++i) {
        const int idx = i * 256 + tid;
        const int r = idx >> 3, c = (idx & 7) * 8;
        *(uint4*)(ob + (size_t)r * DH + c) = *(uint4*)&Os[r * 72 + c];
    }
}

// ---------------------------------------------------------------------------
// Kernel 2.5: Wp fp32 -> bf16 pre-conversion (once; into dead q region).
// ---------------------------------------------------------------------------
__global__ __launch_bounds__(256) void wpconv_kernel(
    const float* __restrict__ Wp, __bf16* __restrict__ Wpb)
{
    const size_t idx = (size_t)(blockIdx.x * 256 + threadIdx.x) * 4;
    const float4 w4 = *(const float4*)(Wp + idx);
    const unsigned lo = ((unsigned)__builtin_bit_cast(unsigned short, (__bf16)w4.y) << 16)
                      | (unsigned)__builtin_bit_cast(unsigned short, (__bf16)w4.x);
    const unsigned hi = ((unsigned)__builtin_bit_cast(unsigned short, (__bf16)w4.w) << 16)
                      | (unsigned)__builtin_bit_cast(unsigned short, (__bf16)w4.z);
    uint2 p; p.x = lo; p.y = hi;
    *(uint2*)(Wpb + idx) = p;
}

// ---------------------------------------------------------------------------
// Kernel 3: output projection, bf16 MFMA. out[tok][e] = A[tok][:].Wpb[e][:]+bp
// Block = 128 tokens x 128 e-cols; K-chunks of 64 (== one head of A).
// DOUBLE-BUFFERED + async-split: one barrier per cb; next-cb global loads
// issued right after the barrier (latency hides under MFMA), ds_write late.
// ---------------------------------------------------------------------------
__global__ __launch_bounds__(256, 2) void proj_kernel(
    const __bf16* __restrict__ a,      // [bh][t][d]
    const __bf16* __restrict__ Wpb, const float* __restrict__ bp,
    float* __restrict__ out)
{
    __shared__ __bf16 As[2][128 * 72];
    __shared__ __bf16 Bs[2][128 * 72];

    const int tb = blockIdx.x, eb = blockIdx.y;
    const int tid = threadIdx.x;
    const int wave = tid >> 6, lane = tid & 63;
    const int m = lane & 31, h = lane >> 5;
    const int tok0 = tb * 128;
    const int b = tok0 >> 11, t0 = tok0 & (T_ - 1);
    const int e0 = eb * 128;

    auto aload = [&](int cb, uint4 (&ar)[4], uint4 (&br)[4]) {
        #pragma unroll
        for (int i = 0; i < 4; ++i) {
            const int idx = i * 256 + tid;
            const int r = idx >> 3, c = (idx & 7) * 8;
            ar[i] = *(const uint4*)(a + ((size_t)(b * H_ + cb) * T_ + t0 + r) * DH + c);
            br[i] = *(const uint4*)(Wpb + (size_t)(e0 + r) * C_ + cb * 64 + c);
        }
    };
    auto astore = [&](int buf, const uint4 (&ar)[4], const uint4 (&br)[4]) {
        #pragma unroll
        for (int i = 0; i < 4; ++i) {
            const int idx = i * 256 + tid;
            const int r = idx >> 3, c = (idx & 7) * 8;
            *(uint4*)&As[buf][r * 72 + c] = ar[i];
            *(uint4*)&Bs[buf][r * 72 + c] = br[i];
        }
    };

    f32x16 acc[4] = {f32x16{}, f32x16{}, f32x16{}, f32x16{}};
    uint4 areg[4], breg[4];

    aload(0, areg, breg);
    astore(0, areg, breg);

    int cur = 0;
    for (int cb = 0; cb < 16; ++cb) {
        __syncthreads();                      // buf[cur] fully staged
        if (cb < 15) aload(cb + 1, areg, breg);   // issue early (hidden)

        #pragma unroll
        for (int ks = 0; ks < 4; ++ks) {
            const bf16x8 af = *(const bf16x8*)&As[cur][(wave * 32 + m) * 72 + ks * 16 + h * 8];
            #pragma unroll
            for (int n = 0; n < 4; ++n) {
                const bf16x8 bf = *(const bf16x8*)&Bs[cur][(n * 32 + m) * 72 + ks * 16 + h * 8];
                acc[n] = MFMA32(af, bf, acc[n]);
            }
        }

        if (cb < 15) astore(cur ^ 1, areg, breg); // land late
        cur ^= 1;
    }

    #pragma unroll
    for (int n = 0; n < 4; ++n) {
        const int e = e0 + n * 32 + m;
        const float bias = bp[e];
        #pragma unroll
        for (int r = 0; r < 16; ++r) {
            const int R = (r & 3) + 8 * (r >> 2) + 4 * h;
            out[(size_t)(tok0 + wave * 32 + R) * C_ + e] = acc[n][r] + bias;
        }
    }
}

// ---------------------------------------------------------------------------
// Workspace (bf16): q | kf | vf | attn_out, each B*H*T*DH = 8388608 elems
// -> 64 MiB total. wqkv (24 KB) reuses ows (dead until attn);
// Wpb (2 MiB) reuses qws (dead after attn).
// ---------------------------------------------------------------------------
extern "C" void kernel_launch(void* const* d_in, const int* in_sizes, int n_in,
                              void* d_out, int out_size, void* d_ws, size_t ws_size,
                              hipStream_t stream)
{
    const float* x  = (const float*)d_in[0];
    const float* Wq = (const float*)d_in[1];
    const float* bq = (const float*)d_in[2];
    const float* Wk = (const float*)d_in[3];
    const float* bk = (const float*)d_in[4];
    const float* Wv = (const float*)d_in[5];
    const float* bv = (const float*)d_in[6];
    const float* Wp = (const float*)d_in[7];
    const float* bp = (const float*)d_in[8];

    const size_t N = (size_t)BH * T_ * DH;
    __bf16* qws  = (__bf16*)d_ws;
    __bf16* kws  = qws + N;
    __bf16* vtws = kws + N;
    __bf16* ows  = vtws + N;
    __bf16* wqkv = ows;                 // dead until attn writes ows
    __bf16* wpb  = qws;                 // q dead after attn

    wconv_kernel<<<dim3(12), 256, 0, stream>>>(Wq, Wk, Wv, wqkv);
    qkv_kernel<<<dim3(16, 64), 256, 0, stream>>>(
        x, wqkv, bq, bk, bv, qws, kws, vtws);
    attn_kernel<<<dim3(64, 16), 256, 0, stream>>>(qws, kws, vtws, ows);
    wpconv_kernel<<<dim3(1024), 256, 0, stream>>>(Wp, wpb);
    proj_kernel<<<dim3(64, 8), 256, 0, stream>>>(ows, wpb, bp, (float*)d_out);
}

// Round 7
// 248.699 us; speedup vs baseline: 1.0447x; 1.0447x over previous
//
#include <hip/hip_runtime.h>
#include <hip/hip_bf16.h>
#include <cstddef>

// Problem constants (SelfAttention: B=4, T=2048, H=16, Dh=64, C=1024)
#define B_  4
#define T_  2048
#define H_  16
#define DH  64
#define C_  1024
#define BH  64    // B_*H_

typedef float  f32x16 __attribute__((ext_vector_type(16)));
typedef __bf16 bf16x8 __attribute__((ext_vector_type(8)));
typedef __bf16 bf16x4 __attribute__((ext_vector_type(4)));

#define MFMA32(a, b, c) __builtin_amdgcn_mfma_f32_32x32x16_bf16(a, b, c, 0, 0, 0)

// mfma_f32_32x32x16_bf16 layouts (cdna4_isa / m74,m101 verified C/D):
//   A[m][k]: m = lane&31, k = (lane>>5)*8 + j   (8 bf16 per lane, b128)
//   B[k][n]: n = lane&31, k = (lane>>5)*8 + j
//   C/D:     col = lane&31, row = (reg&3) + 8*(reg>>2) + 4*(lane>>5)
//
// FRAGMENT-MAJOR global layouts (a fragment load = base + lane*16B -> one
// coalesced 1KB transaction per wave):
//   Kf[bh][kt64][rh][ks][lane][8]   (K rows,   QK^T A-operand)
//   Vf[bh][kt64][dh][c ][lane][8]   (V^T rows, PV A-operand)
//   Af[b*256+bh16*16+qt][wv][ks][lane][8]  (attn out, proj A-operand)
//   Wpf[eb][cb][n][ks][lane][8]     (Wp,      proj B-operand)

__device__ __forceinline__ unsigned cvt_pk_bf16(float lo, float hi) {
    unsigned r;
    asm("v_cvt_pk_bf16_f32 %0, %1, %2" : "=v"(r) : "v"(lo), "v"(hi));
    return r;
}

// ---------------------------------------------------------------------------
// Kernel 0: Wq/Wk/Wv fp32 -> bf16 pre-conversion (once; into dead ows region).
// ---------------------------------------------------------------------------
__global__ __launch_bounds__(256) void wconv_kernel(
    const float* __restrict__ Wq, const float* __restrict__ Wk,
    const float* __restrict__ Wv, __bf16* __restrict__ wqkv)
{
    const int tid = blockIdx.x * 256 + threadIdx.x;   // 0..3071
    const float* srcs[3] = {Wq, Wk, Wv};
    const int mat = tid >> 10;                        // 1024 threads per matrix
    const int off = (tid & 1023) * 4;
    const float4 w4 = *(const float4*)(srcs[mat] + off);
    const unsigned lo = ((unsigned)__builtin_bit_cast(unsigned short, (__bf16)w4.y) << 16)
                      | (unsigned)__builtin_bit_cast(unsigned short, (__bf16)w4.x);
    const unsigned hi = ((unsigned)__builtin_bit_cast(unsigned short, (__bf16)w4.w) << 16)
                      | (unsigned)__builtin_bit_cast(unsigned short, (__bf16)w4.z);
    uint2 p; p.x = lo; p.y = hi;
    *(uint2*)(wqkv + mat * 4096 + off) = p;
}

// ---------------------------------------------------------------------------
// Kernel 1: QKV projection, bf16 MFMA. Block = (128-token tile, one head).
// q written [bh][t][d] with (1/sqrt(C))*log2(e) folded (attention uses exp2).
// k and v written fragment-major via LDS transposes. Weights pre-converted.
// ---------------------------------------------------------------------------
__global__ __launch_bounds__(256) void qkv_kernel(
    const float* __restrict__ x,
    const __bf16* __restrict__ wqkv,
    const float* __restrict__ bq, const float* __restrict__ bk,
    const float* __restrict__ bv,
    __bf16* __restrict__ q, __bf16* __restrict__ kf, __bf16* __restrict__ vf)
{
    __shared__ __bf16 Xs[128 * 72];          // x tile [t_local][d], bf16
    __shared__ __bf16 Ws[3][64 * 72];        // W[e][d], bf16
    __bf16* Vtl = Xs;                         // alias: V^T [e][t_local], stride 136
    __bf16* Kst = &Ws[0][0];                  // alias after mat loop: K [t_local][d], stride 72

    const int tt  = blockIdx.x;               // 0..15 (128-token tile)
    const int bh  = blockIdx.y;               // 0..63
    const int b   = bh >> 4, h = bh & 15;
    const int t0  = tt * 128;
    const int tid = threadIdx.x;
    const int wave = tid >> 6, lane = tid & 63;
    const int m = lane & 31, hh = lane >> 5;

    // stage x (fp32 -> bf16): 128 rows x 64 cols = 2048 float4 chunks
    #pragma unroll
    for (int i = 0; i < 8; ++i) {
        const int idx = i * 256 + tid;
        const int r = idx >> 4, c = (idx & 15) * 4;
        const float4 x4 = *(const float4*)(x + ((size_t)(b * T_ + t0 + r)) * C_ + h * DH + c);
        const unsigned lo = ((unsigned)__builtin_bit_cast(unsigned short, (__bf16)x4.y) << 16)
                          | (unsigned)__builtin_bit_cast(unsigned short, (__bf16)x4.x);
        const unsigned hi = ((unsigned)__builtin_bit_cast(unsigned short, (__bf16)x4.w) << 16)
                          | (unsigned)__builtin_bit_cast(unsigned short, (__bf16)x4.z);
        *(unsigned*)&Xs[r * 72 + c]     = lo;
        *(unsigned*)&Xs[r * 72 + c + 2] = hi;
    }
    // stage weights (already bf16): 3 x 64 x 64 = 1536 uint4 chunks
    #pragma unroll
    for (int i = 0; i < 6; ++i) {
        const int idx = i * 256 + tid;
        const int mat_ = idx >> 9;            // 0..2
        const int r = (idx >> 3) & 63, c = (idx & 7) * 8;
        *(uint4*)&Ws[mat_][r * 72 + c] = *(const uint4*)(wqkv + mat_ * 4096 + r * 64 + c);
    }
    __syncthreads();

    // hoist x A-fragments (wave-private rows 32*wave + m)
    bf16x8 xf[4];
    #pragma unroll
    for (int ks = 0; ks < 4; ++ks)
        xf[ks] = *(const bf16x8*)&Xs[(wave * 32 + m) * 72 + ks * 16 + hh * 8];
    __syncthreads();   // all frag reads done before Vtl aliases Xs

    // 1/sqrt(1024) * log2(e) folded into q (attention uses exp2 directly)
    const float s32 = 0.03125f * 1.4426950408889634f;

    unsigned kpk[16];   // packed k results, staged to LDS after the mat loop

    #pragma unroll
    for (int mat = 0; mat < 3; ++mat) {
        f32x16 acc0 = {}, acc1 = {};
        #pragma unroll
        for (int ks = 0; ks < 4; ++ks) {
            const bf16x8 w0 = *(const bf16x8*)&Ws[mat][(m) * 72 + ks * 16 + hh * 8];
            const bf16x8 w1 = *(const bf16x8*)&Ws[mat][(32 + m) * 72 + ks * 16 + hh * 8];
            acc0 = MFMA32(xf[ks], w0, acc0);
            acc1 = MFMA32(xf[ks], w1, acc1);
        }
        const float* bias = (mat == 0) ? bq : (mat == 1) ? bk : bv;
        const float b0 = bias[m], b1 = bias[32 + m];
        #pragma unroll
        for (int r = 0; r < 16; ++r) {
            const int R = (r & 3) + 8 * (r >> 2) + 4 * hh;   // token row in tile
            const int tloc = wave * 32 + R;
            const float v0 = acc0[r] + b0, v1 = acc1[r] + b1;
            if (mat == 0) {
                const size_t base = ((size_t)bh * T_ + t0 + tloc) * DH;
                q[base + m]      = (__bf16)(v0 * s32);
                q[base + 32 + m] = (__bf16)(v1 * s32);
            } else if (mat == 1) {
                kpk[r] = ((unsigned)__builtin_bit_cast(unsigned short, (__bf16)v1) << 16)
                       |  (unsigned)__builtin_bit_cast(unsigned short, (__bf16)v0);
            } else {
                Vtl[(m) * 136 + tloc]      = (__bf16)v0;   // V^T [e][t_local]
                Vtl[(32 + m) * 136 + tloc] = (__bf16)v1;
            }
        }
    }
    __syncthreads();   // Ws reads done (mat loop), Vtl complete

    // stage k tile [t_local][d] into Kst (Ws area, now dead)
    #pragma unroll
    for (int r = 0; r < 16; ++r) {
        const int R = (r & 3) + 8 * (r >> 2) + 4 * hh;
        const int tloc = wave * 32 + R;
        Kst[tloc * 72 + m]      = __builtin_bit_cast(__bf16, (unsigned short)(kpk[r] & 0xffff));
        Kst[tloc * 72 + 32 + m] = __builtin_bit_cast(__bf16, (unsigned short)(kpk[r] >> 16));
    }

    // Vf fragment-major out (reads Vtl; no barrier needed vs Kst region)
    #pragma unroll
    for (int i = 0; i < 4; ++i) {
        const int idx = i * 256 + tid;
        const int ln = idx & 63, c_ = idx >> 6;           // c_ 0..15
        const int kt64l = c_ >> 3, dh = (c_ >> 2) & 1, cN = c_ & 3;
        const __bf16* src = &Vtl[(dh * 32 + (ln & 31)) * 136 + kt64l * 64 + cN * 16 + (ln >> 5) * 8];
        __bf16* dst = vf + ((((size_t)(bh * 32 + tt * 2 + kt64l) * 2 + dh) * 4 + cN) * 64 + ln) * 8;
        *(uint4*)dst = *(const uint4*)src;
    }
    __syncthreads();   // Kst visible

    // Kf fragment-major out (reads Kst)
    #pragma unroll
    for (int i = 0; i < 4; ++i) {
        const int idx = i * 256 + tid;
        const int ln = idx & 63, c_ = idx >> 6;
        const int kt64l = c_ >> 3, rh = (c_ >> 2) & 1, ks = c_ & 3;
        const __bf16* src = &Kst[(kt64l * 64 + rh * 32 + (ln & 31)) * 72 + ks * 16 + (ln >> 5) * 8];
        __bf16* dst = kf + ((((size_t)(bh * 32 + tt * 2 + kt64l) * 2 + rh) * 4 + ks) * 64 + ln) * 8;
        *(uint4*)dst = *(const uint4*)src;
    }
}

// ---------------------------------------------------------------------------
// Kernel 2: flash attention (main loop UNCHANGED from round 5: MfmaUtil 32%,
// 89-91 us). Epilogue now stores O FRAGMENT-MAJOR (Af) so proj can read its
// A-operand with coalesced lane*16B loads -- same transpose-store volume as
// the old row-major store.
// ---------------------------------------------------------------------------
__global__ __launch_bounds__(256, 4) void attn_kernel(
    const __bf16* __restrict__ q, const __bf16* __restrict__ kf,
    const __bf16* __restrict__ vf, __bf16* __restrict__ af)
{
    __shared__ __bf16 Os[128 * 72];          // epilogue transpose buffer

    const int bh  = blockIdx.x;              // XCD-locality axis (id%8 == bh%8)
    const int q0  = blockIdx.y * 128;
    const int tid = threadIdx.x;
    const int wave = tid >> 6, lane = tid & 63;
    const int m = lane & 31, h = lane >> 5;

    const __bf16* qb  = q  + (size_t)bh * T_ * DH;
    const __bf16* kfb = kf + (size_t)bh * (T_ * DH);   // [kt64][rh][ks][lane][8]
    const __bf16* vfb = vf + (size_t)bh * (T_ * DH);   // [kt64][dh][c ][lane][8]

    // Q fragments (one-time; [t][d] layout, segmented but negligible)
    bf16x8 qf[4];
    #pragma unroll
    for (int ks = 0; ks < 4; ++ks)
        qf[ks] = *(const bf16x8*)(qb + (size_t)(q0 + wave * 32 + m) * DH + ks * 16 + h * 8);

    f32x16 O0 = {}, O1 = {};                 // O^T [d 0..31 | 32..63][q]
    float lsum = 0.f;

    for (int kt = 0; kt < 32; ++kt) {
        const __bf16* kt_k = kfb + kt * 4096;
        const __bf16* kt_v = vfb + kt * 4096;
        #pragma unroll
        for (int rh = 0; rh < 2; ++rh) {
            bf16x8 kfr[4];
            #pragma unroll
            for (int ks = 0; ks < 4; ++ks)
                kfr[ks] = *(const bf16x8*)(kt_k + rh * 2048 + ks * 512 + lane * 8);
            f32x16 S = {};
            #pragma unroll
            for (int ks = 0; ks < 4; ++ks)
                S = MFMA32(kfr[ks], qf[ks], S);

            #pragma unroll
            for (int cc = 0; cc < 2; ++cc) {
                const int rb = cc * 8;
                float e0 = __builtin_amdgcn_exp2f(S[rb + 0]);
                float e1 = __builtin_amdgcn_exp2f(S[rb + 1]);
                float e2 = __builtin_amdgcn_exp2f(S[rb + 2]);
                float e3 = __builtin_amdgcn_exp2f(S[rb + 3]);
                float e4 = __builtin_amdgcn_exp2f(S[rb + 4]);
                float e5 = __builtin_amdgcn_exp2f(S[rb + 5]);
                float e6 = __builtin_amdgcn_exp2f(S[rb + 6]);
                float e7 = __builtin_amdgcn_exp2f(S[rb + 7]);
                lsum += ((e0 + e1) + (e2 + e3)) + ((e4 + e5) + (e6 + e7));
                unsigned a0 = cvt_pk_bf16(e0, e1);
                unsigned a1 = cvt_pk_bf16(e2, e3);
                unsigned b0 = cvt_pk_bf16(e4, e5);
                unsigned b1 = cvt_pk_bf16(e6, e7);
                asm("v_permlane32_swap_b32 %0, %1" : "+v"(a0), "+v"(b0));
                asm("v_permlane32_swap_b32 %0, %1" : "+v"(a1), "+v"(b1));
                const uint4 pw = {a0, a1, b0, b1};
                const bf16x8 pb = __builtin_bit_cast(bf16x8, pw);
                const int c = rh * 2 + cc;          // kv 16-slot
                const bf16x8 v0 = *(const bf16x8*)(kt_v + c * 512 + lane * 8);
                const bf16x8 v1 = *(const bf16x8*)(kt_v + 2048 + c * 512 + lane * 8);
                O0 = MFMA32(v0, pb, O0);
                O1 = MFMA32(v1, pb, O1);
            }
        }
    }

    // l[q]: lanes l and l+32 hold complementary kv halves of the same q-row
    lsum += __shfl_xor(lsum, 32);
    const float linv = 1.0f / lsum;

    // O^T -> LDS: lane owns q-row (wave*32 + m); reg r -> d = (r&3)+8*(r>>2)+4h
    #pragma unroll
    for (int g = 0; g < 4; ++g) {
        bf16x4 w0, w1;
        #pragma unroll
        for (int j = 0; j < 4; ++j) {
            w0[j] = (__bf16)(O0[4 * g + j] * linv);
            w1[j] = (__bf16)(O1[4 * g + j] * linv);
        }
        const int row = (wave * 32 + m) * 72;
        *(bf16x4*)&Os[row + 8 * g + 4 * h]      = w0;
        *(bf16x4*)&Os[row + 32 + 8 * g + 4 * h] = w1;
    }
    __syncthreads();

    // fragment-major store: Af[(bh*16+qtile)][wv][ks][ln][8]
    // 4 wv x 4 ks x 64 ln = 1024 uint4 chunks / 256 threads (coalesced dst)
    __bf16* ab = af + ((size_t)(bh * 16 + (q0 >> 7))) * 8192;
    #pragma unroll
    for (int i = 0; i < 4; ++i) {
        const int idx = i * 256 + tid;
        const int ln = idx & 63, c_ = idx >> 6;       // c_ = wv*4+ks
        const int wv = c_ >> 2, ks = c_ & 3;
        const __bf16* src = &Os[(wv * 32 + (ln & 31)) * 72 + ks * 16 + (ln >> 5) * 8];
        *(uint4*)(ab + c_ * 512 + ln * 8) = *(const uint4*)src;
    }
}

// ---------------------------------------------------------------------------
// Kernel 2.5: Wp fp32 -> bf16 FRAGMENT-MAJOR pre-conversion (once).
// Wpf[eb][cb][n][ks][lane][8]: elem = Wp[eb*128+n*32+(lane&31)]
//                                      [cb*64+ks*16+(lane>>5)*8 + j]
// ---------------------------------------------------------------------------
__global__ __launch_bounds__(256) void wpconv_kernel(
    const float* __restrict__ Wp, __bf16* __restrict__ wpf)
{
    const int gtid = blockIdx.x * 256 + threadIdx.x;   // 32768 threads
    #pragma unroll
    for (int i = 0; i < 4; ++i) {
        const int ci = gtid + i * 32768;               // chunk 0..131071
        const int ln = ci & 63;
        const int ks = (ci >> 6) & 3;
        const int n  = (ci >> 8) & 3;
        const int cb = (ci >> 10) & 15;
        const int eb = ci >> 14;
        const int row = eb * 128 + n * 32 + (ln & 31);
        const int col = cb * 64 + ks * 16 + (ln >> 5) * 8;
        const float4 w0 = *(const float4*)(Wp + (size_t)row * C_ + col);
        const float4 w1 = *(const float4*)(Wp + (size_t)row * C_ + col + 4);
        uint4 p;
        p.x = ((unsigned)__builtin_bit_cast(unsigned short, (__bf16)w0.y) << 16)
            |  (unsigned)__builtin_bit_cast(unsigned short, (__bf16)w0.x);
        p.y = ((unsigned)__builtin_bit_cast(unsigned short, (__bf16)w0.w) << 16)
            |  (unsigned)__builtin_bit_cast(unsigned short, (__bf16)w0.z);
        p.z = ((unsigned)__builtin_bit_cast(unsigned short, (__bf16)w1.y) << 16)
            |  (unsigned)__builtin_bit_cast(unsigned short, (__bf16)w1.x);
        p.w = ((unsigned)__builtin_bit_cast(unsigned short, (__bf16)w1.w) << 16)
            |  (unsigned)__builtin_bit_cast(unsigned short, (__bf16)w1.z);
        *(uint4*)(wpf + (size_t)ci * 8) = p;
    }
}

// ---------------------------------------------------------------------------
// Kernel 3: output projection, bf16 MFMA, LDS-FREE / BARRIER-FREE main loop
// (attn-style). out[tok][e] = A[tok][:].Wp[e][:] + bp.
// Block = 128 tokens x 128 e-cols, 4 waves x (32 tok x 128 e) each.
// A and Wp read fragment-major from global: every fragment load is one
// coalesced 1KB wave transaction, L1/L2-served (A tile shared by 8 eb-blocks
// on one XCD: grid x = tb -> id%8 = tb%8).
// ---------------------------------------------------------------------------
__global__ __launch_bounds__(256) void proj_kernel(
    const __bf16* __restrict__ af,     // Af fragment-major
    const __bf16* __restrict__ wpf,    // Wpf fragment-major
    const float* __restrict__ bp,
    float* __restrict__ out)
{
    const int tb = blockIdx.x, eb = blockIdx.y;
    const int tid = threadIdx.x;
    const int wave = tid >> 6, lane = tid & 63;
    const int m = lane & 31, h = lane >> 5;
    const int tok0 = tb * 128;
    const int b = tb >> 4, qtile = tb & 15;
    const int e0 = eb * 128;

    // per-lane bases: cb advances Af by 16*8192 (head stride in Af) and
    // Wpf by 8192.
    const __bf16* abase = af + ((size_t)(b * 256 + qtile)) * 8192
                             + (wave * 4) * 512 + lane * 8;
    const __bf16* wbase = wpf + (size_t)eb * 131072 + lane * 8;

    f32x16 acc[4] = {f32x16{}, f32x16{}, f32x16{}, f32x16{}};

    for (int cb = 0; cb < 16; ++cb) {
        const __bf16* ap = abase + (size_t)cb * 131072;   // 16 qtiles * 8192
        const __bf16* wp = wbase + (size_t)cb * 8192;
        bf16x8 afr[4];
        #pragma unroll
        for (int ks = 0; ks < 4; ++ks)
            afr[ks] = *(const bf16x8*)(ap + ks * 512);
        #pragma unroll
        for (int n = 0; n < 4; ++n) {
            #pragma unroll
            for (int ks = 0; ks < 4; ++ks) {
                const bf16x8 bf = *(const bf16x8*)(wp + (n * 4 + ks) * 512);
                acc[n] = MFMA32(afr[ks], bf, acc[n]);
            }
        }
    }

    #pragma unroll
    for (int n = 0; n < 4; ++n) {
        const int e = e0 + n * 32 + m;
        const float bias = bp[e];
        #pragma unroll
        for (int r = 0; r < 16; ++r) {
            const int R = (r & 3) + 8 * (r >> 2) + 4 * h;
            out[(size_t)(tok0 + wave * 32 + R) * C_ + e] = acc[n][r] + bias;
        }
    }
}

// ---------------------------------------------------------------------------
// Workspace (bf16): q | kf | vf | af, each B*H*T*DH = 8388608 elems
// -> 64 MiB total. wqkv (24 KB) reuses af region (dead until attn);
// wpf (2 MiB) reuses q region (dead after attn).
// ---------------------------------------------------------------------------
extern "C" void kernel_launch(void* const* d_in, const int* in_sizes, int n_in,
                              void* d_out, int out_size, void* d_ws, size_t ws_size,
                              hipStream_t stream)
{
    const float* x  = (const float*)d_in[0];
    const float* Wq = (const float*)d_in[1];
    const float* bq = (const float*)d_in[2];
    const float* Wk = (const float*)d_in[3];
    const float* bk = (const float*)d_in[4];
    const float* Wv = (const float*)d_in[5];
    const float* bv = (const float*)d_in[6];
    const float* Wp = (const float*)d_in[7];
    const float* bp = (const float*)d_in[8];

    const size_t N = (size_t)BH * T_ * DH;
    __bf16* qws  = (__bf16*)d_ws;
    __bf16* kws  = qws + N;
    __bf16* vtws = kws + N;
    __bf16* aws  = vtws + N;
    __bf16* wqkv = aws;                 // dead until attn writes aws
    __bf16* wpf  = qws;                 // q dead after attn

    wconv_kernel<<<dim3(12), 256, 0, stream>>>(Wq, Wk, Wv, wqkv);
    qkv_kernel<<<dim3(16, 64), 256, 0, stream>>>(
        x, wqkv, bq, bk, bv, qws, kws, vtws);
    attn_kernel<<<dim3(64, 16), 256, 0, stream>>>(qws, kws, vtws, aws);
    wpconv_kernel<<<dim3(128), 256, 0, stream>>>(Wp, wpf);
    proj_kernel<<<dim3(64, 8), 256, 0, stream>>>(aws, wpf, bp, (float*)d_out);
}

// Round 8
// 230.079 us; speedup vs baseline: 1.1292x; 1.0809x over previous
//
#include <hip/hip_runtime.h>
#include <hip/hip_bf16.h>
#include <cstddef>

// Problem constants (SelfAttention: B=4, T=2048, H=16, Dh=64, C=1024)
#define B_  4
#define T_  2048
#define H_  16
#define DH  64
#define C_  1024
#define BH  64    // B_*H_

typedef float  f32x16 __attribute__((ext_vector_type(16)));
typedef __bf16 bf16x8 __attribute__((ext_vector_type(8)));
typedef __bf16 bf16x4 __attribute__((ext_vector_type(4)));

#define MFMA32(a, b, c) __builtin_amdgcn_mfma_f32_32x32x16_bf16(a, b, c, 0, 0, 0)

// mfma_f32_32x32x16_bf16 layouts (cdna4_isa / m74,m101 verified C/D):
//   A[m][k]: m = lane&31, k = (lane>>5)*8 + j   (8 bf16 per lane, b128)
//   B[k][n]: n = lane&31, k = (lane>>5)*8 + j
//   C/D:     col = lane&31, row = (reg&3) + 8*(reg>>2) + 4*(lane>>5)
//
// FRAGMENT-MAJOR global layouts (a fragment load = base + lane*16B -> one
// coalesced 1KB transaction per wave):
//   Kf[bh][kt64][rh][ks][lane][8]   (K rows,   QK^T A-operand)
//   Vf[bh][kt64][dh][c ][lane][8]   (V^T rows, PV A-operand)
//   Af[(bh/16)*256+cb*16+qt][wv][ks][lane][8]  (attn out, proj A-operand)
//   Wpf[eb][cb][n][ks][lane][8]     (Wp,      proj B-operand)

__device__ __forceinline__ unsigned cvt_pk_bf16(float lo, float hi) {
    unsigned r;
    asm("v_cvt_pk_bf16_f32 %0, %1, %2" : "=v"(r) : "v"(lo), "v"(hi));
    return r;
}

// ---------------------------------------------------------------------------
// Kernel 0: Wq/Wk/Wv fp32 -> bf16 pre-conversion (once; into dead af region).
// ---------------------------------------------------------------------------
__global__ __launch_bounds__(256) void wconv_kernel(
    const float* __restrict__ Wq, const float* __restrict__ Wk,
    const float* __restrict__ Wv, __bf16* __restrict__ wqkv)
{
    const int tid = blockIdx.x * 256 + threadIdx.x;   // 0..3071
    const float* srcs[3] = {Wq, Wk, Wv};
    const int mat = tid >> 10;                        // 1024 threads per matrix
    const int off = (tid & 1023) * 4;
    const float4 w4 = *(const float4*)(srcs[mat] + off);
    const unsigned lo = ((unsigned)__builtin_bit_cast(unsigned short, (__bf16)w4.y) << 16)
                      | (unsigned)__builtin_bit_cast(unsigned short, (__bf16)w4.x);
    const unsigned hi = ((unsigned)__builtin_bit_cast(unsigned short, (__bf16)w4.w) << 16)
                      | (unsigned)__builtin_bit_cast(unsigned short, (__bf16)w4.z);
    uint2 p; p.x = lo; p.y = hi;
    *(uint2*)(wqkv + mat * 4096 + off) = p;
}

// ---------------------------------------------------------------------------
// Kernel 1: QKV projection, bf16 MFMA (UNCHANGED from round 7).
// ---------------------------------------------------------------------------
__global__ __launch_bounds__(256) void qkv_kernel(
    const float* __restrict__ x,
    const __bf16* __restrict__ wqkv,
    const float* __restrict__ bq, const float* __restrict__ bk,
    const float* __restrict__ bv,
    __bf16* __restrict__ q, __bf16* __restrict__ kf, __bf16* __restrict__ vf)
{
    __shared__ __bf16 Xs[128 * 72];          // x tile [t_local][d], bf16
    __shared__ __bf16 Ws[3][64 * 72];        // W[e][d], bf16
    __bf16* Vtl = Xs;                         // alias: V^T [e][t_local], stride 136
    __bf16* Kst = &Ws[0][0];                  // alias after mat loop: K [t_local][d], stride 72

    const int tt  = blockIdx.x;               // 0..15 (128-token tile)
    const int bh  = blockIdx.y;               // 0..63
    const int b   = bh >> 4, h = bh & 15;
    const int t0  = tt * 128;
    const int tid = threadIdx.x;
    const int wave = tid >> 6, lane = tid & 63;
    const int m = lane & 31, hh = lane >> 5;

    // stage x (fp32 -> bf16): 128 rows x 64 cols = 2048 float4 chunks
    #pragma unroll
    for (int i = 0; i < 8; ++i) {
        const int idx = i * 256 + tid;
        const int r = idx >> 4, c = (idx & 15) * 4;
        const float4 x4 = *(const float4*)(x + ((size_t)(b * T_ + t0 + r)) * C_ + h * DH + c);
        const unsigned lo = ((unsigned)__builtin_bit_cast(unsigned short, (__bf16)x4.y) << 16)
                          | (unsigned)__builtin_bit_cast(unsigned short, (__bf16)x4.x);
        const unsigned hi = ((unsigned)__builtin_bit_cast(unsigned short, (__bf16)x4.w) << 16)
                          | (unsigned)__builtin_bit_cast(unsigned short, (__bf16)x4.z);
        *(unsigned*)&Xs[r * 72 + c]     = lo;
        *(unsigned*)&Xs[r * 72 + c + 2] = hi;
    }
    // stage weights (already bf16): 3 x 64 x 64 = 1536 uint4 chunks
    #pragma unroll
    for (int i = 0; i < 6; ++i) {
        const int idx = i * 256 + tid;
        const int mat_ = idx >> 9;            // 0..2
        const int r = (idx >> 3) & 63, c = (idx & 7) * 8;
        *(uint4*)&Ws[mat_][r * 72 + c] = *(const uint4*)(wqkv + mat_ * 4096 + r * 64 + c);
    }
    __syncthreads();

    // hoist x A-fragments (wave-private rows 32*wave + m)
    bf16x8 xf[4];
    #pragma unroll
    for (int ks = 0; ks < 4; ++ks)
        xf[ks] = *(const bf16x8*)&Xs[(wave * 32 + m) * 72 + ks * 16 + hh * 8];
    __syncthreads();   // all frag reads done before Vtl aliases Xs

    // 1/sqrt(1024) * log2(e) folded into q (attention uses exp2 directly)
    const float s32 = 0.03125f * 1.4426950408889634f;

    unsigned kpk[16];   // packed k results, staged to LDS after the mat loop

    #pragma unroll
    for (int mat = 0; mat < 3; ++mat) {
        f32x16 acc0 = {}, acc1 = {};
        #pragma unroll
        for (int ks = 0; ks < 4; ++ks) {
            const bf16x8 w0 = *(const bf16x8*)&Ws[mat][(m) * 72 + ks * 16 + hh * 8];
            const bf16x8 w1 = *(const bf16x8*)&Ws[mat][(32 + m) * 72 + ks * 16 + hh * 8];
            acc0 = MFMA32(xf[ks], w0, acc0);
            acc1 = MFMA32(xf[ks], w1, acc1);
        }
        const float* bias = (mat == 0) ? bq : (mat == 1) ? bk : bv;
        const float b0 = bias[m], b1 = bias[32 + m];
        #pragma unroll
        for (int r = 0; r < 16; ++r) {
            const int R = (r & 3) + 8 * (r >> 2) + 4 * hh;   // token row in tile
            const int tloc = wave * 32 + R;
            const float v0 = acc0[r] + b0, v1 = acc1[r] + b1;
            if (mat == 0) {
                const size_t base = ((size_t)bh * T_ + t0 + tloc) * DH;
                q[base + m]      = (__bf16)(v0 * s32);
                q[base + 32 + m] = (__bf16)(v1 * s32);
            } else if (mat == 1) {
                kpk[r] = ((unsigned)__builtin_bit_cast(unsigned short, (__bf16)v1) << 16)
                       |  (unsigned)__builtin_bit_cast(unsigned short, (__bf16)v0);
            } else {
                Vtl[(m) * 136 + tloc]      = (__bf16)v0;   // V^T [e][t_local]
                Vtl[(32 + m) * 136 + tloc] = (__bf16)v1;
            }
        }
    }
    __syncthreads();   // Ws reads done (mat loop), Vtl complete

    // stage k tile [t_local][d] into Kst (Ws area, now dead)
    #pragma unroll
    for (int r = 0; r < 16; ++r) {
        const int R = (r & 3) + 8 * (r >> 2) + 4 * hh;
        const int tloc = wave * 32 + R;
        Kst[tloc * 72 + m]      = __builtin_bit_cast(__bf16, (unsigned short)(kpk[r] & 0xffff));
        Kst[tloc * 72 + 32 + m] = __builtin_bit_cast(__bf16, (unsigned short)(kpk[r] >> 16));
    }

    // Vf fragment-major out (reads Vtl; no barrier needed vs Kst region)
    #pragma unroll
    for (int i = 0; i < 4; ++i) {
        const int idx = i * 256 + tid;
        const int ln = idx & 63, c_ = idx >> 6;           // c_ 0..15
        const int kt64l = c_ >> 3, dh = (c_ >> 2) & 1, cN = c_ & 3;
        const __bf16* src = &Vtl[(dh * 32 + (ln & 31)) * 136 + kt64l * 64 + cN * 16 + (ln >> 5) * 8];
        __bf16* dst = vf + ((((size_t)(bh * 32 + tt * 2 + kt64l) * 2 + dh) * 4 + cN) * 64 + ln) * 8;
        *(uint4*)dst = *(const uint4*)src;
    }
    __syncthreads();   // Kst visible

    // Kf fragment-major out (reads Kst)
    #pragma unroll
    for (int i = 0; i < 4; ++i) {
        const int idx = i * 256 + tid;
        const int ln = idx & 63, c_ = idx >> 6;
        const int kt64l = c_ >> 3, rh = (c_ >> 2) & 1, ks = c_ & 3;
        const __bf16* src = &Kst[(kt64l * 64 + rh * 32 + (ln & 31)) * 72 + ks * 16 + (ln >> 5) * 8];
        __bf16* dst = kf + ((((size_t)(bh * 32 + tt * 2 + kt64l) * 2 + rh) * 4 + ks) * 64 + ln) * 8;
        *(uint4*)dst = *(const uint4*)src;
    }
}

// ---------------------------------------------------------------------------
// Kernel 2: flash attention, SPLIT-KV x2.
// Block = 256 thr = 4 waves = (2 q-slices of 32 rows) x (2 kv-halves of 1024).
// Grid (64 bh, 32 qy) = 2048 blocks -> 8192 waves (2x the old structural cap
// of 16 waves/CU). No max-tracking => split-kv merge is EXACT: O and l add.
// kv1 waves write f32 partials to LDS; kv0 waves add, normalize, and write
// Af directly from registers via cvt_pk + permlane32_swap (the O-reg d-group
// structure matches the P-path exactly) -- no LDS transpose, coalesced 1KB
// fragment stores.
// ---------------------------------------------------------------------------
__global__ __launch_bounds__(256, 4) void attn_kernel(
    const __bf16* __restrict__ q, const __bf16* __restrict__ kf,
    const __bf16* __restrict__ vf, __bf16* __restrict__ af)
{
    __shared__ float OL[2][64 * 36];    // kv1 partials [qs][lane*36 + r], 18.4 KB
    __shared__ float LL[2][64];         // kv1 partial lsums

    const int bh  = blockIdx.x;         // XCD-locality axis (id%8 == bh%8)
    const int q0  = blockIdx.y * 64;
    const int tid = threadIdx.x;
    const int wave = tid >> 6, lane = tid & 63;
    const int m = lane & 31, h = lane >> 5;
    const int qs  = wave & 1;           // q 32-row slice within the 64-row tile
    const int kvh = wave >> 1;          // kv half (1024 keys each)

    const __bf16* qb  = q  + (size_t)bh * T_ * DH;
    const __bf16* kfb = kf + (size_t)bh * (T_ * DH);   // [kt64][rh][ks][lane][8]
    const __bf16* vfb = vf + (size_t)bh * (T_ * DH);   // [kt64][dh][c ][lane][8]

    // Q fragments (one-time)
    bf16x8 qf[4];
    #pragma unroll
    for (int ks = 0; ks < 4; ++ks)
        qf[ks] = *(const bf16x8*)(qb + (size_t)(q0 + qs * 32 + m) * DH + ks * 16 + h * 8);

    f32x16 O0 = {}, O1 = {};            // O^T [d 0..31 | 32..63][q] (partial)
    float lsum = 0.f;

    const int ktEnd = kvh * 16 + 16;
    for (int kt = kvh * 16; kt < ktEnd; ++kt) {
        const __bf16* kt_k = kfb + kt * 4096;
        const __bf16* kt_v = vfb + kt * 4096;
        #pragma unroll
        for (int rh = 0; rh < 2; ++rh) {
            bf16x8 kfr[4];
            #pragma unroll
            for (int ks = 0; ks < 4; ++ks)
                kfr[ks] = *(const bf16x8*)(kt_k + rh * 2048 + ks * 512 + lane * 8);
            f32x16 S = {};
            #pragma unroll
            for (int ks = 0; ks < 4; ++ks)
                S = MFMA32(kfr[ks], qf[ks], S);

            #pragma unroll
            for (int cc = 0; cc < 2; ++cc) {
                const int rb = cc * 8;
                float e0 = __builtin_amdgcn_exp2f(S[rb + 0]);
                float e1 = __builtin_amdgcn_exp2f(S[rb + 1]);
                float e2 = __builtin_amdgcn_exp2f(S[rb + 2]);
                float e3 = __builtin_amdgcn_exp2f(S[rb + 3]);
                float e4 = __builtin_amdgcn_exp2f(S[rb + 4]);
                float e5 = __builtin_amdgcn_exp2f(S[rb + 5]);
                float e6 = __builtin_amdgcn_exp2f(S[rb + 6]);
                float e7 = __builtin_amdgcn_exp2f(S[rb + 7]);
                lsum += ((e0 + e1) + (e2 + e3)) + ((e4 + e5) + (e6 + e7));
                unsigned a0 = cvt_pk_bf16(e0, e1);
                unsigned a1 = cvt_pk_bf16(e2, e3);
                unsigned b0 = cvt_pk_bf16(e4, e5);
                unsigned b1 = cvt_pk_bf16(e6, e7);
                asm("v_permlane32_swap_b32 %0, %1" : "+v"(a0), "+v"(b0));
                asm("v_permlane32_swap_b32 %0, %1" : "+v"(a1), "+v"(b1));
                const uint4 pw = {a0, a1, b0, b1};
                const bf16x8 pb = __builtin_bit_cast(bf16x8, pw);
                const int c = rh * 2 + cc;          // kv 16-slot
                const bf16x8 v0 = *(const bf16x8*)(kt_v + c * 512 + lane * 8);
                const bf16x8 v1 = *(const bf16x8*)(kt_v + 2048 + c * 512 + lane * 8);
                O0 = MFMA32(v0, pb, O0);
                O1 = MFMA32(v1, pb, O1);
            }
        }
    }

    // split-kv merge (exact: no max-tracking, partials just add)
    if (kvh == 1) {
        #pragma unroll
        for (int g = 0; g < 4; ++g) {
            float4 p0, p1;
            p0.x = O0[4 * g];     p0.y = O0[4 * g + 1];
            p0.z = O0[4 * g + 2]; p0.w = O0[4 * g + 3];
            p1.x = O1[4 * g];     p1.y = O1[4 * g + 1];
            p1.z = O1[4 * g + 2]; p1.w = O1[4 * g + 3];
            *(float4*)&OL[qs][lane * 36 + 4 * g]      = p0;
            *(float4*)&OL[qs][lane * 36 + 16 + 4 * g] = p1;
        }
        LL[qs][lane] = lsum;
    }
    __syncthreads();
    if (kvh == 0) {
        #pragma unroll
        for (int g = 0; g < 4; ++g) {
            const float4 p0 = *(const float4*)&OL[qs][lane * 36 + 4 * g];
            const float4 p1 = *(const float4*)&OL[qs][lane * 36 + 16 + 4 * g];
            O0[4 * g]     += p0.x; O0[4 * g + 1] += p0.y;
            O0[4 * g + 2] += p0.z; O0[4 * g + 3] += p0.w;
            O1[4 * g]     += p1.x; O1[4 * g + 1] += p1.y;
            O1[4 * g + 2] += p1.z; O1[4 * g + 3] += p1.w;
        }
        lsum += LL[qs][lane];
        lsum += __shfl_xor(lsum, 32);   // lanes l, l+32: complementary kv rows
        const float linv = 1.0f / lsum;

        // Af store straight from registers: per ks, pack 8 d-values and
        // permlane-swap h-halves (identical structure to the P-path).
        // wv = (q0/32) 32-row slice = (blockIdx.y&1)*2 + qs.
        __bf16* ab = af + ((size_t)(bh * 16 + (q0 >> 7))) * 8192
                        + (((q0 >> 6) & 1) * 2 + qs) * 2048 + lane * 8;
        #pragma unroll
        for (int ks = 0; ks < 4; ++ks) {
            const f32x16& Og = (ks < 2) ? O0 : O1;
            const int rb = (ks & 1) * 8;
            unsigned a0 = cvt_pk_bf16(Og[rb + 0] * linv, Og[rb + 1] * linv);
            unsigned a1 = cvt_pk_bf16(Og[rb + 2] * linv, Og[rb + 3] * linv);
            unsigned b0 = cvt_pk_bf16(Og[rb + 4] * linv, Og[rb + 5] * linv);
            unsigned b1 = cvt_pk_bf16(Og[rb + 6] * linv, Og[rb + 7] * linv);
            asm("v_permlane32_swap_b32 %0, %1" : "+v"(a0), "+v"(b0));
            asm("v_permlane32_swap_b32 %0, %1" : "+v"(a1), "+v"(b1));
            const uint4 pw = {a0, a1, b0, b1};
            *(uint4*)(ab + ks * 512) = pw;
        }
    }
}

// ---------------------------------------------------------------------------
// Kernel 2.5: Wp fp32 -> bf16 FRAGMENT-MAJOR pre-conversion (once).
// 512 blocks, 1 chunk/thread: scattered reads hidden by TLP (was 128 blocks
// = 0.5 block/CU, latency-bound).
// ---------------------------------------------------------------------------
__global__ __launch_bounds__(256) void wpconv_kernel(
    const float* __restrict__ Wp, __bf16* __restrict__ wpf)
{
    const int ci = blockIdx.x * 256 + threadIdx.x;     // chunk 0..131071
    const int ln = ci & 63;
    const int ks = (ci >> 6) & 3;
    const int n  = (ci >> 8) & 3;
    const int cb = (ci >> 10) & 15;
    const int eb = ci >> 14;
    const int row = eb * 128 + n * 32 + (ln & 31);
    const int col = cb * 64 + ks * 16 + (ln >> 5) * 8;
    const float4 w0 = *(const float4*)(Wp + (size_t)row * C_ + col);
    const float4 w1 = *(const float4*)(Wp + (size_t)row * C_ + col + 4);
    uint4 p;
    p.x = ((unsigned)__builtin_bit_cast(unsigned short, (__bf16)w0.y) << 16)
        |  (unsigned)__builtin_bit_cast(unsigned short, (__bf16)w0.x);
    p.y = ((unsigned)__builtin_bit_cast(unsigned short, (__bf16)w0.w) << 16)
        |  (unsigned)__builtin_bit_cast(unsigned short, (__bf16)w0.z);
    p.z = ((unsigned)__builtin_bit_cast(unsigned short, (__bf16)w1.y) << 16)
        |  (unsigned)__builtin_bit_cast(unsigned short, (__bf16)w1.x);
    p.w = ((unsigned)__builtin_bit_cast(unsigned short, (__bf16)w1.w) << 16)
        |  (unsigned)__builtin_bit_cast(unsigned short, (__bf16)w1.z);
    *(uint4*)(wpf + (size_t)ci * 8) = p;
}

// ---------------------------------------------------------------------------
// Kernel 3: output projection, bf16 MFMA, LDS/barrier-free.
// Block = 64 tokens x 128 e-cols; grid (128, 8) = 1024 blocks = 4 blocks/CU
// (was 512 = 2/CU, latency-bound). Waves specialize (wv-slice, e-half):
// per cb each wave does 4 af + 8 wpf coalesced fragment loads + 8 MFMA;
// wpf redundancy across waves halved vs the 128-token version.
// ---------------------------------------------------------------------------
__global__ __launch_bounds__(256) void proj_kernel(
    const __bf16* __restrict__ af,     // Af fragment-major
    const __bf16* __restrict__ wpf,    // Wpf fragment-major
    const float* __restrict__ bp,
    float* __restrict__ out)
{
    const int tb2 = blockIdx.x, eb = blockIdx.y;
    const int tid = threadIdx.x;
    const int wave = tid >> 6, lane = tid & 63;
    const int m = lane & 31, h = lane >> 5;
    const int b = tb2 >> 5, rem = tb2 & 31;
    const int qtile = rem >> 1, half = rem & 1;
    const int wv = half * 2 + (wave & 1);   // 32-row token slice
    const int eh = wave >> 1;               // 64-col e half
    const int e0 = eb * 128;

    const __bf16* abase = af + ((size_t)(b * 256 + qtile)) * 8192
                             + wv * 2048 + lane * 8;
    const __bf16* wbase = wpf + (size_t)eb * 131072 + eh * 4096 + lane * 8;

    f32x16 acc[2] = {f32x16{}, f32x16{}};

    for (int cb = 0; cb < 16; ++cb) {
        const __bf16* ap = abase + (size_t)cb * 131072;   // 16 qtiles * 8192
        const __bf16* wp = wbase + (size_t)cb * 8192;
        bf16x8 afr[4];
        #pragma unroll
        for (int ks = 0; ks < 4; ++ks)
            afr[ks] = *(const bf16x8*)(ap + ks * 512);
        #pragma unroll
        for (int n = 0; n < 2; ++n) {
            #pragma unroll
            for (int ks = 0; ks < 4; ++ks) {
                const bf16x8 bf = *(const bf16x8*)(wp + (n * 4 + ks) * 512);
                acc[n] = MFMA32(afr[ks], bf, acc[n]);
            }
        }
    }

    const int tokbase = b * T_ + qtile * 128 + wv * 32;
    #pragma unroll
    for (int n = 0; n < 2; ++n) {
        const int e = e0 + (eh * 2 + n) * 32 + m;
        const float bias = bp[e];
        #pragma unroll
        for (int r = 0; r < 16; ++r) {
            const int R = (r & 3) + 8 * (r >> 2) + 4 * h;
            out[(size_t)(tokbase + R) * C_ + e] = acc[n][r] + bias;
        }
    }
}

// ---------------------------------------------------------------------------
// Workspace (bf16): q | kf | vf | af, each B*H*T*DH = 8388608 elems
// -> 64 MiB total. wqkv (24 KB) reuses af region (dead until attn);
// wpf (2 MiB) reuses q region (dead after attn).
// ---------------------------------------------------------------------------
extern "C" void kernel_launch(void* const* d_in, const int* in_sizes, int n_in,
                              void* d_out, int out_size, void* d_ws, size_t ws_size,
                              hipStream_t stream)
{
    const float* x  = (const float*)d_in[0];
    const float* Wq = (const float*)d_in[1];
    const float* bq = (const float*)d_in[2];
    const float* Wk = (const float*)d_in[3];
    const float* bk = (const float*)d_in[4];
    const float* Wv = (const float*)d_in[5];
    const float* bv = (const float*)d_in[6];
    const float* Wp = (const float*)d_in[7];
    const float* bp = (const float*)d_in[8];

    const size_t N = (size_t)BH * T_ * DH;
    __bf16* qws  = (__bf16*)d_ws;
    __bf16* kws  = qws + N;
    __bf16* vtws = kws + N;
    __bf16* aws  = vtws + N;
    __bf16* wqkv = aws;                 // dead until attn writes aws
    __bf16* wpf  = qws;                 // q dead after attn

    wconv_kernel<<<dim3(12), 256, 0, stream>>>(Wq, Wk, Wv, wqkv);
    qkv_kernel<<<dim3(16, 64), 256, 0, stream>>>(
        x, wqkv, bq, bk, bv, qws, kws, vtws);
    attn_kernel<<<dim3(64, 32), 256, 0, stream>>>(qws, kws, vtws, aws);
    wpconv_kernel<<<dim3(512), 256, 0, stream>>>(Wp, wpf);
    proj_kernel<<<dim3(128, 8), 256, 0, stream>>>(aws, wpf, bp, (float*)d_out);
}